// Round 8
// baseline (167.336 us; speedup 1.0000x reference)
//
#include <hip/hip_runtime.h>

typedef __bf16 bf16x8 __attribute__((ext_vector_type(8)));
typedef float f32x4 __attribute__((ext_vector_type(4)));
typedef unsigned short u16;

#define LSEQ 2048
#define DMODEL 1024
#define HEADD 64
#define NBATCH 8

__device__ __forceinline__ u16 cvt(float f) {
  __bf16 h = (__bf16)f;               // native v_cvt (RNE)
  return __builtin_bit_cast(u16, h);
}

// ---------------------------------------------------------------------------
// Probe: calibration only. Perfect-coalesced grid-stride read of all three
// 64MB inputs, TWO passes (384 MB). Sums kept live; 2MB of per-thread sums
// written into the Kb region, which proj_kernel fully overwrites afterwards,
// so the final output is unaffected. Its dur_us (rocprof) = achievable read
// BW in this harness context.
// ---------------------------------------------------------------------------
__global__ __launch_bounds__(256) void probe_kernel(
    const float* __restrict__ a, const float* __restrict__ b,
    const float* __restrict__ c, float* __restrict__ dst) {
  size_t idx = (size_t)blockIdx.x * 256 + threadIdx.x;
  size_t stride = (size_t)gridDim.x * 256;
  const float4* A = (const float4*)a;
  const float4* B = (const float4*)b;
  const float4* C = (const float4*)c;
  float4 s = make_float4(0.f, 0.f, 0.f, 0.f);
#pragma unroll
  for (int pass = 0; pass < 2; ++pass) {
    for (size_t i = idx; i < 4194304; i += stride) {
      float4 v = A[i]; s.x += v.x; s.y += v.y; s.z += v.z; s.w += v.w;
    }
    for (size_t i = idx; i < 4194304; i += stride) {
      float4 v = B[i]; s.x += v.x; s.y += v.y; s.z += v.z; s.w += v.w;
    }
    for (size_t i = idx; i < 4194304; i += stride) {
      float4 v = C[i]; s.x += v.x; s.y += v.y; s.z += v.z; s.w += v.w;
    }
  }
  dst[idx] = s.x + s.y + s.z + s.w;
}

// ---------------------------------------------------------------------------
// Kernel 0: pack W [1024][64] fp32 into MFMA B-FRAGMENT order (bf16):
//   wp[((p*4 + c)*32 + ks)*512 + lane*8 + j] = W_p[k = ks*32 + 8*(lane>>4) + j]
//                                                  [col = 16*c + (lane&15)]
// ---------------------------------------------------------------------------
__global__ __launch_bounds__(256) void wt_kernel(
    const float* __restrict__ Wk, const float* __restrict__ Wq,
    const float* __restrict__ Wv, u16* __restrict__ wp) {
  int idx = blockIdx.x * 256 + threadIdx.x;   // 0 .. 3*4*32*512-1 (196608)
  int j = idx & 7;
  int lane = (idx >> 3) & 63;
  int ks = (idx >> 9) & 31;
  int c = (idx >> 14) & 3;
  int p = idx >> 16;
  const float* W = (p == 0) ? Wk : ((p == 1) ? Wq : Wv);
  int k = ks * 32 + 8 * (lane >> 4) + j;
  int col = 16 * c + (lane & 15);
  wp[idx] = cvt(W[(size_t)k * HEADD + col]);
}

// ---------------------------------------------------------------------------
// Kernel 1: proj = R7 + W staged in LDS (single-variable change).
// Block 256 thr / 4 waves / 64 rows; K chunked by 128. LDS: A dbuf 2x16KB
// (XOR-swizzled) + W dbuf 2x16KB (fragment-packed, linear, conflict-free).
// Per chunk: issue A+W global->reg for NEXT chunk (stay in flight across
// compute), ds_read frags + MFMA for CURRENT chunk, vmcnt(0)+commit+barrier.
// W global traffic: once per BLOCK (was once per WAVE) -> 4x cut.
// p==0 -> K bf16 ; p==1 -> Q*0.125 ; p==2 -> V^T [b][64][2048]
// ---------------------------------------------------------------------------
__global__ __launch_bounds__(256) void proj_kernel(
    const float* __restrict__ ik, const float* __restrict__ iq, const float* __restrict__ iv,
    const u16* __restrict__ wp, u16* __restrict__ Kb, u16* __restrict__ Qb,
    u16* __restrict__ Vt) {
  __shared__ __align__(16) u16 Asw[2][64 * 128];  // 2 x 16 KB swizzled bf16
  __shared__ __align__(16) u16 Wl[2][4 * 2048];   // 2 x 16 KB [c][ks][512]
  int p = blockIdx.y;
  const float* A = (p == 0) ? ik : ((p == 1) ? iq : iv);
  const u16* Wp = wp + (size_t)p * 4 * 32 * 512;   // [c][ks_glob][512]
  int t = threadIdx.x;
  int lane = t & 63;
  int wv = t >> 6;
  int l15 = lane & 15, g = lane >> 4;
  int rowbase = blockIdx.x * 64;
  const float* srcbase = A + (size_t)rowbase * DMODEL;

  // A staging map: piece i (0..7): row = i*8 + (t>>5), float-col = (t&31)*4
  int srow0 = t >> 5;
  int scol = (t & 31) * 4;

  float4 stg[8];
  auto issueA = [&](int kc) {
#pragma unroll
    for (int i = 0; i < 8; ++i) {
      int row = i * 8 + srow0;
      stg[i] = *(const float4*)(srcbase + (size_t)row * DMODEL + kc + scol);
    }
  };
  auto commitA = [&](int buf) {
    char* base = (char*)&Asw[buf][0];
#pragma unroll
    for (int i = 0; i < 8; ++i) {
      int row = i * 8 + srow0;
      ushort4 pk;
      pk.x = cvt(stg[i].x); pk.y = cvt(stg[i].y);
      pk.z = cvt(stg[i].z); pk.w = cvt(stg[i].w);
      int byte = row * 256 + ((scol * 2) ^ ((row & 7) << 4));
      *(ushort4*)(base + byte) = pk;
    }
  };

  // W staging: wave wv stages c-slab wv (4 KB): 4 coalesced 1KB instrs
  uint4 wstg[4];
  auto issueW = [&](int c8) {
    const u16* wsrc = Wp + ((size_t)wv * 32 + c8 * 4) * 512;
#pragma unroll
    for (int i = 0; i < 4; ++i)
      wstg[i] = *(const uint4*)(wsrc + (i * 64 + lane) * 8);
  };
  auto commitW = [&](int buf) {
    u16* wdst = &Wl[buf][wv * 2048];
#pragma unroll
    for (int i = 0; i < 4; ++i)
      *(uint4*)(wdst + (i * 64 + lane) * 8) = wstg[i];
  };

  f32x4 acc[4] = {};  // [c]: row = rowbase+16wv+4g+r, col = 16c+l15
  int arow = 16 * wv + l15;
  int abase = arow * 256;
  int aswz = (l15 & 7) << 4;

  issueA(0);
  issueW(0);
  commitA(0);
  commitW(0);
  __syncthreads();

  for (int c8 = 0; c8 < 8; ++c8) {
    // (1) prefetch NEXT chunk (A: HBM, W: L2) -> registers, stay in flight
    if (c8 < 7) {
      issueA((c8 + 1) * 128);
      issueW(c8 + 1);
    }
    __builtin_amdgcn_sched_barrier(0);

    // (2) compute current chunk entirely from LDS
    const char* lbase = (const char*)&Asw[c8 & 1][0];
    const u16* wbase = &Wl[c8 & 1][0];
#pragma unroll
    for (int ks = 0; ks < 4; ++ks) {
      bf16x8 af = *(const bf16x8*)(lbase + abase + ((ks * 64 + 16 * g) ^ aswz));
#pragma unroll
      for (int c = 0; c < 4; ++c) {
        bf16x8 wf = *(const bf16x8*)(wbase + c * 2048 + ks * 512 + lane * 8);
        acc[c] = __builtin_amdgcn_mfma_f32_16x16x32_bf16(af, wf, acc[c], 0, 0, 0);
      }
    }

    // (3) land prefetch, write LDS, swap
    if (c8 < 7) {
      commitA((c8 + 1) & 1);
      commitW((c8 + 1) & 1);
    }
    __syncthreads();
  }

  int rb2 = rowbase + 16 * wv;
  if (p == 2) {
    // store V transposed: Vt[b][d][tok], pack 4 consecutive tokens -> 8B store
    int row0 = rb2 + 4 * g;
    int b = row0 >> 11, tok = row0 & 2047;
#pragma unroll
    for (int c = 0; c < 4; ++c) {
      int d = 16 * c + l15;
      ushort4 pk;
      pk.x = cvt(acc[c][0]); pk.y = cvt(acc[c][1]);
      pk.z = cvt(acc[c][2]); pk.w = cvt(acc[c][3]);
      *(ushort4*)(Vt + ((size_t)b * HEADD + d) * LSEQ + tok) = pk;
    }
  } else {
    u16* dst = (p == 0) ? Kb : Qb;
    float s = (p == 1) ? 0.125f : 1.0f;  // fold softmax scale into Q (exact pow2)
#pragma unroll
    for (int c = 0; c < 4; ++c)
#pragma unroll
      for (int r = 0; r < 4; ++r)
        dst[(size_t)(rb2 + 4 * g + r) * HEADD + 16 * c + l15] = cvt(acc[c][r] * s);
  }
}

// ---------------------------------------------------------------------------
// Kernel 2: causal flash attention (unchanged).
// ---------------------------------------------------------------------------
__global__ __launch_bounds__(128) void attn_kernel(
    const u16* __restrict__ Kb, const u16* __restrict__ Qb, const u16* __restrict__ Vt,
    float* __restrict__ out) {
  __shared__ __align__(16) u16 plds[2][16 * 40];  // per-wave P tile [16q][32k], pad->40
  int lane = threadIdx.x & 63;
  int wv = threadIdx.x >> 6;
  int l15 = lane & 15, g = lane >> 4;
  int b = blockIdx.y;
  int qt = 63 - (int)blockIdx.x;          // heavy tiles first
  int qbase = qt * 32 + wv * 16;          // within batch

  const u16* Qp = Qb + ((size_t)b * LSEQ + qbase) * HEADD;
  const u16* Kp = Kb + (size_t)b * LSEQ * HEADD;
  const u16* Vp = Vt + (size_t)b * HEADD * LSEQ;

  bf16x8 qf[2];
#pragma unroll
  for (int ds = 0; ds < 2; ++ds)
    qf[ds] = *(const bf16x8*)(Qp + (size_t)l15 * HEADD + 32 * ds + 8 * g);

  f32x4 acc[4] = {};        // [c]: reg r -> q-row qbase+4g+r, col d=16c+l15
  float m = -1e30f, lsum = 0.f;
  int q_abs = qbase + l15;
  int ntiles = (qbase + 47) >> 5;

  for (int t = 0; t < ntiles; ++t) {
    int kbase = t * 32;
    f32x4 sacc[2] = {};     // [f]: key = kbase+16f+4g+r, q = qbase+l15
#pragma unroll
    for (int f = 0; f < 2; ++f)
#pragma unroll
      for (int ds = 0; ds < 2; ++ds) {
        bf16x8 kf = *(const bf16x8*)(Kp + (size_t)(kbase + 16 * f + l15) * HEADD + 32 * ds + 8 * g);
        sacc[f] = __builtin_amdgcn_mfma_f32_16x16x32_bf16(kf, qf[ds], sacc[f], 0, 0, 0);
      }

    // causal mask + row-max (row == this lane's q)
    float sv[2][4];
    float tmax = -1e30f;
#pragma unroll
    for (int f = 0; f < 2; ++f)
#pragma unroll
      for (int r = 0; r < 4; ++r) {
        int key = kbase + 16 * f + 4 * g + r;
        float s = (key <= q_abs) ? sacc[f][r] : -1e30f;
        sv[f][r] = s;
        tmax = fmaxf(tmax, s);
      }
    tmax = fmaxf(tmax, __shfl_xor(tmax, 16));
    tmax = fmaxf(tmax, __shfl_xor(tmax, 32));
    float mnew = fmaxf(m, tmax);
    float al = __expf(m - mnew);
    float pv[2][4];
    float rs = 0.f;
#pragma unroll
    for (int f = 0; f < 2; ++f)
#pragma unroll
      for (int r = 0; r < 4; ++r) {
        pv[f][r] = __expf(sv[f][r] - mnew);
        rs += pv[f][r];
      }
    rs += __shfl_xor(rs, 16);
    rs += __shfl_xor(rs, 32);
    lsum = lsum * al + rs;
    m = mnew;

    // rescale O accumulator: row 4g+r's factor lives at lane (4g+r) (group 0 copy)
    float alr[4];
#pragma unroll
    for (int r = 0; r < 4; ++r) alr[r] = __shfl(al, 4 * g + r);
#pragma unroll
    for (int c = 0; c < 4; ++c)
#pragma unroll
      for (int r = 0; r < 4; ++r) acc[c][r] *= alr[r];

    // P -> LDS in PV A-frag layout: P[q=l15][key 16f+4g + r]
#pragma unroll
    for (int f = 0; f < 2; ++f) {
      ushort4 pk;
      pk.x = cvt(pv[f][0]); pk.y = cvt(pv[f][1]);
      pk.z = cvt(pv[f][2]); pk.w = cvt(pv[f][3]);
      *(ushort4*)&plds[wv][l15 * 40 + 16 * f + 4 * g] = pk;
    }
    bf16x8 ap = *(const bf16x8*)&plds[wv][l15 * 40 + 8 * g];

    // PV: B-frag = V[kbase+8g+j][16c+l15] = Vt[16c+l15][kbase+8g+j] (contiguous)
#pragma unroll
    for (int c = 0; c < 4; ++c) {
      bf16x8 vf = *(const bf16x8*)(Vp + (size_t)(16 * c + l15) * LSEQ + kbase + 8 * g);
      acc[c] = __builtin_amdgcn_mfma_f32_16x16x32_bf16(ap, vf, acc[c], 0, 0, 0);
    }
  }

  // normalize and store fp32 output
  float li[4];
#pragma unroll
  for (int r = 0; r < 4; ++r) {
    float lv = __shfl(lsum, 4 * g + r);
    li[r] = 1.0f / lv;
  }
#pragma unroll
  for (int c = 0; c < 4; ++c)
#pragma unroll
    for (int r = 0; r < 4; ++r)
      out[((size_t)b * LSEQ + qbase + 4 * g + r) * HEADD + 16 * c + l15] = acc[c][r] * li[r];
}

// ---------------------------------------------------------------------------
extern "C" void kernel_launch(void* const* d_in, const int* in_sizes, int n_in,
                              void* d_out, int out_size, void* d_ws, size_t ws_size,
                              hipStream_t stream) {
  const float* idx_k = (const float*)d_in[0];
  const float* idx_q = (const float*)d_in[1];
  const float* idx_v = (const float*)d_in[2];
  // d_in[3] = msk : causal mask is applied analytically, never read
  const float* Wk = (const float*)d_in[4];
  const float* Wq = (const float*)d_in[5];
  const float* Wv = (const float*)d_in[6];
  float* out = (float*)d_out;

  char* ws = (char*)d_ws;
  const size_t WT_BYTES = (size_t)3 * 4 * 32 * 512 * 2;          // 384 KB packed W
  const size_t MAT_BYTES = (size_t)NBATCH * LSEQ * HEADD * 2;    // 2 MB each
  u16* wp = (u16*)ws;
  u16* Kb = (u16*)(ws + WT_BYTES);
  u16* Qb = (u16*)(ws + WT_BYTES + MAT_BYTES);
  u16* Vt = (u16*)(ws + WT_BYTES + 2 * MAT_BYTES);

  // calibration probe (dumps into Kb; proj overwrites Kb afterwards)
  hipLaunchKernelGGL(probe_kernel, dim3(2048), dim3(256), 0, stream,
                     idx_k, idx_q, idx_v, (float*)Kb);
  hipLaunchKernelGGL(wt_kernel, dim3(768), dim3(256), 0, stream, Wk, Wq, Wv, wp);
  hipLaunchKernelGGL(proj_kernel, dim3(256, 3), dim3(256), 0, stream,
                     idx_k, idx_q, idx_v, wp, Kb, Qb, Vt);
  hipLaunchKernelGGL(attn_kernel, dim3(64, NBATCH), dim3(128), 0, stream, Kb, Qb, Vt, out);
}

// Round 9
// 112.285 us; speedup vs baseline: 1.4903x; 1.4903x over previous
//
#include <hip/hip_runtime.h>

typedef __bf16 bf16x8 __attribute__((ext_vector_type(8)));
typedef float f32x4 __attribute__((ext_vector_type(4)));
typedef unsigned short u16;

#define LSEQ 2048
#define DMODEL 1024
#define HEADD 64
#define NBATCH 8

__device__ __forceinline__ u16 cvt(float f) {
  __bf16 h = (__bf16)f;               // native v_cvt (RNE)
  return __builtin_bit_cast(u16, h);
}

// ---------------------------------------------------------------------------
// Kernel 0: pack W [1024][64] fp32 into MFMA B-FRAGMENT order (bf16):
//   wp[((p*4 + c)*32 + ks)*512 + lane*8 + j] = W_p[k = ks*32 + 8*(lane>>4) + j]
//                                                  [col = 16*c + (lane&15)]
// ---------------------------------------------------------------------------
__global__ __launch_bounds__(256) void wt_kernel(
    const float* __restrict__ Wk, const float* __restrict__ Wq,
    const float* __restrict__ Wv, u16* __restrict__ wp) {
  int idx = blockIdx.x * 256 + threadIdx.x;   // 0 .. 3*4*32*512-1 (196608)
  int j = idx & 7;
  int lane = (idx >> 3) & 63;
  int ks = (idx >> 9) & 31;
  int c = (idx >> 14) & 3;
  int p = idx >> 16;
  const float* W = (p == 0) ? Wk : ((p == 1) ? Wq : Wv);
  int k = ks * 32 + 8 * (lane >> 4) + j;
  int col = 16 * c + (lane & 15);
  wp[idx] = cvt(W[(size_t)k * HEADD + col]);
}

// ---------------------------------------------------------------------------
// Kernel 1: proj (unchanged from R8; measured ~51us, near the calibrated
// ~44-55us context read ceiling for the 192MB fp32 inputs).
// Block 256 thr / 4 waves / 64 rows; K chunked by 128. LDS: A dbuf 2x16KB
// (XOR-swizzled) + W dbuf 2x16KB (fragment-packed). Per chunk: prefetch
// next A+W to regs (in flight across compute), MFMA from LDS, commit, swap.
// p==0 -> K bf16 ; p==1 -> Q*0.125 ; p==2 -> V^T [b][64][2048]
// ---------------------------------------------------------------------------
__global__ __launch_bounds__(256) void proj_kernel(
    const float* __restrict__ ik, const float* __restrict__ iq, const float* __restrict__ iv,
    const u16* __restrict__ wp, u16* __restrict__ Kb, u16* __restrict__ Qb,
    u16* __restrict__ Vt) {
  __shared__ __align__(16) u16 Asw[2][64 * 128];  // 2 x 16 KB swizzled bf16
  __shared__ __align__(16) u16 Wl[2][4 * 2048];   // 2 x 16 KB [c][ks][512]
  int p = blockIdx.y;
  const float* A = (p == 0) ? ik : ((p == 1) ? iq : iv);
  const u16* Wp = wp + (size_t)p * 4 * 32 * 512;   // [c][ks_glob][512]
  int t = threadIdx.x;
  int lane = t & 63;
  int wv = t >> 6;
  int l15 = lane & 15, g = lane >> 4;
  int rowbase = blockIdx.x * 64;
  const float* srcbase = A + (size_t)rowbase * DMODEL;

  // A staging map: piece i (0..7): row = i*8 + (t>>5), float-col = (t&31)*4
  int srow0 = t >> 5;
  int scol = (t & 31) * 4;

  float4 stg[8];
  auto issueA = [&](int kc) {
#pragma unroll
    for (int i = 0; i < 8; ++i) {
      int row = i * 8 + srow0;
      stg[i] = *(const float4*)(srcbase + (size_t)row * DMODEL + kc + scol);
    }
  };
  auto commitA = [&](int buf) {
    char* base = (char*)&Asw[buf][0];
#pragma unroll
    for (int i = 0; i < 8; ++i) {
      int row = i * 8 + srow0;
      ushort4 pk;
      pk.x = cvt(stg[i].x); pk.y = cvt(stg[i].y);
      pk.z = cvt(stg[i].z); pk.w = cvt(stg[i].w);
      int byte = row * 256 + ((scol * 2) ^ ((row & 7) << 4));
      *(ushort4*)(base + byte) = pk;
    }
  };

  // W staging: wave wv stages c-slab wv (4 KB): 4 coalesced 1KB instrs
  uint4 wstg[4];
  auto issueW = [&](int c8) {
    const u16* wsrc = Wp + ((size_t)wv * 32 + c8 * 4) * 512;
#pragma unroll
    for (int i = 0; i < 4; ++i)
      wstg[i] = *(const uint4*)(wsrc + (i * 64 + lane) * 8);
  };
  auto commitW = [&](int buf) {
    u16* wdst = &Wl[buf][wv * 2048];
#pragma unroll
    for (int i = 0; i < 4; ++i)
      *(uint4*)(wdst + (i * 64 + lane) * 8) = wstg[i];
  };

  f32x4 acc[4] = {};  // [c]: row = rowbase+16wv+4g+r, col = 16c+l15
  int arow = 16 * wv + l15;
  int abase = arow * 256;
  int aswz = (l15 & 7) << 4;

  issueA(0);
  issueW(0);
  commitA(0);
  commitW(0);
  __syncthreads();

  for (int c8 = 0; c8 < 8; ++c8) {
    // (1) prefetch NEXT chunk (A: HBM, W: L2) -> registers, stay in flight
    if (c8 < 7) {
      issueA((c8 + 1) * 128);
      issueW(c8 + 1);
    }
    __builtin_amdgcn_sched_barrier(0);

    // (2) compute current chunk entirely from LDS
    const char* lbase = (const char*)&Asw[c8 & 1][0];
    const u16* wbase = &Wl[c8 & 1][0];
#pragma unroll
    for (int ks = 0; ks < 4; ++ks) {
      bf16x8 af = *(const bf16x8*)(lbase + abase + ((ks * 64 + 16 * g) ^ aswz));
#pragma unroll
      for (int c = 0; c < 4; ++c) {
        bf16x8 wf = *(const bf16x8*)(wbase + c * 2048 + ks * 512 + lane * 8);
        acc[c] = __builtin_amdgcn_mfma_f32_16x16x32_bf16(af, wf, acc[c], 0, 0, 0);
      }
    }

    // (3) land prefetch, write LDS, swap
    if (c8 < 7) {
      commitA((c8 + 1) & 1);
      commitW((c8 + 1) & 1);
    }
    __syncthreads();
  }

  int rb2 = rowbase + 16 * wv;
  if (p == 2) {
    // store V transposed: Vt[b][d][tok], pack 4 consecutive tokens -> 8B store
    int row0 = rb2 + 4 * g;
    int b = row0 >> 11, tok = row0 & 2047;
#pragma unroll
    for (int c = 0; c < 4; ++c) {
      int d = 16 * c + l15;
      ushort4 pk;
      pk.x = cvt(acc[c][0]); pk.y = cvt(acc[c][1]);
      pk.z = cvt(acc[c][2]); pk.w = cvt(acc[c][3]);
      *(ushort4*)(Vt + ((size_t)b * HEADD + d) * LSEQ + tok) = pk;
    }
  } else {
    u16* dst = (p == 0) ? Kb : Qb;
    float s = (p == 1) ? 0.125f : 1.0f;  // fold softmax scale into Q (exact pow2)
#pragma unroll
    for (int c = 0; c < 4; ++c)
#pragma unroll
      for (int r = 0; r < 4; ++r)
        dst[(size_t)(rb2 + 4 * g + r) * HEADD + 16 * c + l15] = cvt(acc[c][r] * s);
  }
}

// ---------------------------------------------------------------------------
// Kernel 2: causal flash attention, register-double-buffered K/V.
// 2 waves/block, wave owns 16 q-rows. Tile t+1's K AND V loads issue before
// tile t's compute -> L2 latency hides under softmax+PV (was fully serial).
// Wave-uniform mask-skip for full tiles; exact skip-rescale when running
// max doesn't grow. Swapped QK^T; P via padded per-wave LDS; V^T contiguous.
// ---------------------------------------------------------------------------
__global__ __launch_bounds__(128) void attn_kernel(
    const u16* __restrict__ Kb, const u16* __restrict__ Qb, const u16* __restrict__ Vt,
    float* __restrict__ out) {
  __shared__ __align__(16) u16 plds[2][16 * 40];  // per-wave P tile [16q][32k], pad->40
  int lane = threadIdx.x & 63;
  int wv = threadIdx.x >> 6;
  int l15 = lane & 15, g = lane >> 4;
  int b = blockIdx.y;
  int qt = 63 - (int)blockIdx.x;          // heavy tiles first
  int qbase = qt * 32 + wv * 16;          // within batch

  const u16* Qp = Qb + ((size_t)b * LSEQ + qbase) * HEADD;
  const u16* Kp = Kb + (size_t)b * LSEQ * HEADD;
  const u16* Vp = Vt + (size_t)b * HEADD * LSEQ;

  bf16x8 qf[2];
#pragma unroll
  for (int ds = 0; ds < 2; ++ds)
    qf[ds] = *(const bf16x8*)(Qp + (size_t)l15 * HEADD + 32 * ds + 8 * g);

  f32x4 acc[4] = {};        // [c]: reg r -> q-row qbase+4g+r, col d=16c+l15
  float m = -1e30f, lsum = 0.f;
  int q_abs = qbase + l15;
  int ntiles = (qbase + 47) >> 5;

  bf16x8 ka[4], va[4], kb2[4], vb2[4];  // k idx = f*2+ds

  auto loadKV = [&](bf16x8 (&kr)[4], bf16x8 (&vr)[4], int t) {
    int kbase = t * 32;
#pragma unroll
    for (int f = 0; f < 2; ++f)
#pragma unroll
      for (int ds = 0; ds < 2; ++ds)
        kr[f * 2 + ds] = *(const bf16x8*)(Kp + (size_t)(kbase + 16 * f + l15) * HEADD + 32 * ds + 8 * g);
#pragma unroll
    for (int c = 0; c < 4; ++c)
      vr[c] = *(const bf16x8*)(Vp + (size_t)(16 * c + l15) * LSEQ + kbase + 8 * g);
  };

  auto compute = [&](const bf16x8 (&kr)[4], const bf16x8 (&vr)[4], int t) {
    int kbase = t * 32;
    f32x4 sacc[2] = {};     // [f]: key = kbase+16f+4g+r, q = qbase+l15
#pragma unroll
    for (int f = 0; f < 2; ++f)
#pragma unroll
      for (int ds = 0; ds < 2; ++ds)
        sacc[f] = __builtin_amdgcn_mfma_f32_16x16x32_bf16(kr[f * 2 + ds], qf[ds], sacc[f], 0, 0, 0);

    // causal mask + row-max; skip per-element select on fully-valid tiles
    float sv[2][4];
    float tmax = -1e30f;
    if (kbase + 32 <= qbase) {
#pragma unroll
      for (int f = 0; f < 2; ++f)
#pragma unroll
        for (int r = 0; r < 4; ++r) {
          sv[f][r] = sacc[f][r];
          tmax = fmaxf(tmax, sv[f][r]);
        }
    } else {
#pragma unroll
      for (int f = 0; f < 2; ++f)
#pragma unroll
        for (int r = 0; r < 4; ++r) {
          int key = kbase + 16 * f + 4 * g + r;
          float s = (key <= q_abs) ? sacc[f][r] : -1e30f;
          sv[f][r] = s;
          tmax = fmaxf(tmax, s);
        }
    }
    tmax = fmaxf(tmax, __shfl_xor(tmax, 16));
    tmax = fmaxf(tmax, __shfl_xor(tmax, 32));

    bool skip = __all(tmax <= m);           // exact defer: max didn't grow
    float mnew = skip ? m : fmaxf(m, tmax);

    float pv[2][4];
    float rs = 0.f;
#pragma unroll
    for (int f = 0; f < 2; ++f)
#pragma unroll
      for (int r = 0; r < 4; ++r) {
        pv[f][r] = __expf(sv[f][r] - mnew);
        rs += pv[f][r];
      }
    rs += __shfl_xor(rs, 16);
    rs += __shfl_xor(rs, 32);

    if (skip) {
      lsum += rs;
    } else {
      float al = __expf(m - mnew);
      float alr[4];
#pragma unroll
      for (int r = 0; r < 4; ++r) alr[r] = __shfl(al, 4 * g + r);
#pragma unroll
      for (int c = 0; c < 4; ++c)
#pragma unroll
        for (int r = 0; r < 4; ++r) acc[c][r] *= alr[r];
      lsum = lsum * al + rs;
      m = mnew;
    }

    // P -> LDS in PV A-frag layout: P[q=l15][key 16f+4g + r]
#pragma unroll
    for (int f = 0; f < 2; ++f) {
      ushort4 pk;
      pk.x = cvt(pv[f][0]); pk.y = cvt(pv[f][1]);
      pk.z = cvt(pv[f][2]); pk.w = cvt(pv[f][3]);
      *(ushort4*)&plds[wv][l15 * 40 + 16 * f + 4 * g] = pk;
    }
    bf16x8 ap = *(const bf16x8*)&plds[wv][l15 * 40 + 8 * g];

#pragma unroll
    for (int c = 0; c < 4; ++c)
      acc[c] = __builtin_amdgcn_mfma_f32_16x16x32_bf16(ap, vr[c], acc[c], 0, 0, 0);
  };

  loadKV(ka, va, 0);
  int t = 0;
  for (; t + 1 < ntiles; t += 2) {
    loadKV(kb2, vb2, t + 1);          // issue next-tile loads (stay in flight)
    compute(ka, va, t);               // compute current from regs
    if (t + 2 < ntiles) loadKV(ka, va, t + 2);
    compute(kb2, vb2, t + 1);
  }
  if (t < ntiles) compute(ka, va, t);

  // normalize and store fp32 output
  float li[4];
#pragma unroll
  for (int r = 0; r < 4; ++r) {
    float lv = __shfl(lsum, 4 * g + r);
    li[r] = 1.0f / lv;
  }
#pragma unroll
  for (int c = 0; c < 4; ++c)
#pragma unroll
    for (int r = 0; r < 4; ++r)
      out[((size_t)b * LSEQ + qbase + 4 * g + r) * HEADD + 16 * c + l15] = acc[c][r] * li[r];
}

// ---------------------------------------------------------------------------
extern "C" void kernel_launch(void* const* d_in, const int* in_sizes, int n_in,
                              void* d_out, int out_size, void* d_ws, size_t ws_size,
                              hipStream_t stream) {
  const float* idx_k = (const float*)d_in[0];
  const float* idx_q = (const float*)d_in[1];
  const float* idx_v = (const float*)d_in[2];
  // d_in[3] = msk : causal mask is applied analytically, never read
  const float* Wk = (const float*)d_in[4];
  const float* Wq = (const float*)d_in[5];
  const float* Wv = (const float*)d_in[6];
  float* out = (float*)d_out;

  char* ws = (char*)d_ws;
  const size_t WT_BYTES = (size_t)3 * 4 * 32 * 512 * 2;          // 384 KB packed W
  const size_t MAT_BYTES = (size_t)NBATCH * LSEQ * HEADD * 2;    // 2 MB each
  u16* wp = (u16*)ws;
  u16* Kb = (u16*)(ws + WT_BYTES);
  u16* Qb = (u16*)(ws + WT_BYTES + MAT_BYTES);
  u16* Vt = (u16*)(ws + WT_BYTES + 2 * MAT_BYTES);

  hipLaunchKernelGGL(wt_kernel, dim3(768), dim3(256), 0, stream, Wk, Wq, Wv, wp);
  hipLaunchKernelGGL(proj_kernel, dim3(256, 3), dim3(256), 0, stream,
                     idx_k, idx_q, idx_v, wp, Kb, Qb, Vt);
  hipLaunchKernelGGL(attn_kernel, dim3(64, NBATCH), dim3(128), 0, stream, Kb, Qb, Vt, out);
}

// Round 10
// 102.941 us; speedup vs baseline: 1.6256x; 1.0908x over previous
//
#include <hip/hip_runtime.h>

typedef __bf16 bf16x8 __attribute__((ext_vector_type(8)));
typedef float f32x4 __attribute__((ext_vector_type(4)));
typedef unsigned short u16;

#define LSEQ 2048
#define DMODEL 1024
#define HEADD 64
#define NBATCH 8

__device__ __forceinline__ u16 cvt(float f) {
  __bf16 h = (__bf16)f;               // native v_cvt (RNE)
  return __builtin_bit_cast(u16, h);
}

// Raw workgroup barrier draining ONLY LDS counters: in-flight global loads
// (the 2-deep A prefetch) survive the barrier. __syncthreads would emit
// s_waitcnt vmcnt(0) and drain the pipeline every chunk (m97 stall).
#define BARRIER_LGKM() do {                                   \
    asm volatile("s_waitcnt lgkmcnt(0)" ::: "memory");        \
    __builtin_amdgcn_sched_barrier(0);                        \
    __builtin_amdgcn_s_barrier();                             \
    __builtin_amdgcn_sched_barrier(0);                        \
  } while (0)

// ---------------------------------------------------------------------------
// Kernel 0: pack W [1024][64] fp32 into MFMA B-FRAGMENT order (bf16):
//   wp[((p*4 + c)*32 + ks)*512 + lane*8 + j] = W_p[k = ks*32 + 8*(lane>>4) + j]
//                                                  [col = 16*c + (lane&15)]
// ---------------------------------------------------------------------------
__global__ __launch_bounds__(256) void wt_kernel(
    const float* __restrict__ Wk, const float* __restrict__ Wq,
    const float* __restrict__ Wv, u16* __restrict__ wp) {
  int idx = blockIdx.x * 256 + threadIdx.x;   // 0 .. 3*4*32*512-1 (196608)
  int j = idx & 7;
  int lane = (idx >> 3) & 63;
  int ks = (idx >> 9) & 31;
  int c = (idx >> 14) & 3;
  int p = idx >> 16;
  const float* W = (p == 0) ? Wk : ((p == 1) ? Wq : Wv);
  int k = ks * 32 + 8 * (lane >> 4) + j;
  int col = 16 * c + (lane & 15);
  wp[idx] = cvt(W[(size_t)k * HEADD + col]);
}

// ---------------------------------------------------------------------------
// Kernel 1: projections. 2-deep prefetch + lgkm-only barriers.
// Block 256 thr / 4 waves / 64 rows; K chunked by 128 (8 chunks).
// LDS: A dbuf 2x16KB XOR-swizzled only (32 KB total).
// Per chunk: W-frags (L2, 1KB contiguous) load FIRST (oldest in vmcnt FIFO),
// then issue A for chunk+2 (youngest, stays in flight >=2 compute phases),
// compute waits vmcnt(8) only, commit writes chunk+1's staged regs to LDS,
// raw barrier drains lgkmcnt only. stgA/stgB named (rule #20: no runtime
// indexing of register arrays).
// p==0 -> K bf16 ; p==1 -> Q*0.125 ; p==2 -> V^T [b][64][2048]
// ---------------------------------------------------------------------------
__global__ __launch_bounds__(256) void proj_kernel(
    const float* __restrict__ ik, const float* __restrict__ iq, const float* __restrict__ iv,
    const u16* __restrict__ wp, u16* __restrict__ Kb, u16* __restrict__ Qb,
    u16* __restrict__ Vt) {
  __shared__ __align__(16) u16 Asw[2][64 * 128];  // 2 x 16 KB swizzled bf16
  int p = blockIdx.y;
  const float* A = (p == 0) ? ik : ((p == 1) ? iq : iv);
  const u16* Wp = wp + (size_t)p * 4 * 32 * 512;   // [c][ks_glob][512]
  int t = threadIdx.x;
  int lane = t & 63;
  int wv = t >> 6;
  int l15 = lane & 15, g = lane >> 4;
  int rowbase = blockIdx.x * 64;
  const float* srcbase = A + (size_t)rowbase * DMODEL;

  // A staging map: piece i (0..7): row = i*8 + (t>>5), float-col = (t&31)*4
  int srow0 = t >> 5;
  int scol = (t & 31) * 4;

  float4 stgA[8], stgB[8];
  bf16x8 wfr[4][4];

  auto issue = [&](float4 (&stg)[8], int kc) {
#pragma unroll
    for (int i = 0; i < 8; ++i)
      stg[i] = *(const float4*)(srcbase + (size_t)(i * 8 + srow0) * DMODEL + kc + scol);
  };
  auto commit = [&](const float4 (&stg)[8], u16* basep) {
    char* base = (char*)basep;
#pragma unroll
    for (int i = 0; i < 8; ++i) {
      int row = i * 8 + srow0;
      ushort4 pk;
      pk.x = cvt(stg[i].x); pk.y = cvt(stg[i].y);
      pk.z = cvt(stg[i].z); pk.w = cvt(stg[i].w);
      int byte = row * 256 + ((scol * 2) ^ ((row & 7) << 4));
      *(ushort4*)(base + byte) = pk;
    }
  };
  auto wload = [&](int c8) {
#pragma unroll
    for (int ks = 0; ks < 4; ++ks)
#pragma unroll
      for (int c = 0; c < 4; ++c)
        wfr[ks][c] = *(const bf16x8*)(Wp + ((size_t)c * 32 + c8 * 4 + ks) * 512 + lane * 8);
  };

  f32x4 acc[4] = {};  // [c]: row = rowbase+16wv+4g+r, col = 16c+l15
  int abase = (16 * wv + l15) * 256;
  int aswz = (l15 & 7) << 4;

  auto computeC = [&](const char* lbase) {
#pragma unroll
    for (int ks = 0; ks < 4; ++ks) {
      bf16x8 af = *(const bf16x8*)(lbase + abase + ((ks * 64 + 16 * g) ^ aswz));
#pragma unroll
      for (int c = 0; c < 4; ++c)
        acc[c] = __builtin_amdgcn_mfma_f32_16x16x32_bf16(af, wfr[ks][c], acc[c], 0, 0, 0);
    }
  };

  // prologue: stgA=kc0, stgB=kc1; commit kc0; barrier
  issue(stgA, 0);
  issue(stgB, 128);
  commit(stgA, &Asw[0][0]);
  BARRIER_LGKM();

#pragma unroll 1
  for (int cc = 0; cc < 8; cc += 2) {
    // ---- even chunk c8 = cc : compute buf0 ----
    wload(cc);                                   // oldest in vmcnt queue
    __builtin_amdgcn_sched_barrier(0);
    if (cc < 6) issue(stgA, (cc + 2) * 128);     // youngest: in flight 2 phases
    __builtin_amdgcn_sched_barrier(0);
    computeC((const char*)&Asw[0][0]);           // waits vmcnt(8) for W only
    commit(stgB, &Asw[1][0]);                    // kc = cc+1 (landed long ago)
    BARRIER_LGKM();
    // ---- odd chunk c8 = cc+1 : compute buf1 ----
    wload(cc + 1);
    __builtin_amdgcn_sched_barrier(0);
    if (cc < 5) issue(stgB, (cc + 3) * 128);
    __builtin_amdgcn_sched_barrier(0);
    computeC((const char*)&Asw[1][0]);
    if (cc < 6) commit(stgA, &Asw[0][0]);        // kc = cc+2
    BARRIER_LGKM();
  }

  int rb2 = rowbase + 16 * wv;
  if (p == 2) {
    // store V transposed: Vt[b][d][tok], pack 4 consecutive tokens -> 8B store
    int row0 = rb2 + 4 * g;
    int b = row0 >> 11, tok = row0 & 2047;
#pragma unroll
    for (int c = 0; c < 4; ++c) {
      int d = 16 * c + l15;
      ushort4 pk;
      pk.x = cvt(acc[c][0]); pk.y = cvt(acc[c][1]);
      pk.z = cvt(acc[c][2]); pk.w = cvt(acc[c][3]);
      *(ushort4*)(Vt + ((size_t)b * HEADD + d) * LSEQ + tok) = pk;
    }
  } else {
    u16* dst = (p == 0) ? Kb : Qb;
    float s = (p == 1) ? 0.125f : 1.0f;  // fold softmax scale into Q (exact pow2)
#pragma unroll
    for (int c = 0; c < 4; ++c)
#pragma unroll
      for (int r = 0; r < 4; ++r)
        dst[(size_t)(rb2 + 4 * g + r) * HEADD + 16 * c + l15] = cvt(acc[c][r] * s);
  }
}

// ---------------------------------------------------------------------------
// Kernel 2: causal flash attention with per-block SPLIT-K.
// Block = 2 waves SHARING one 16-row q-tile; wave w handles k-tiles t%2==w.
// Longest serial chain halves (64 -> 32 tiles); waves/CU double to 8.
// Merge (m, l, acc) via LDS at the end (wave1 publishes, wave0 combines).
// Swapped QK^T; P via padded per-wave LDS; V^T contiguous B-frags.
// ---------------------------------------------------------------------------
__global__ __launch_bounds__(128) void attn_kernel(
    const u16* __restrict__ Kb, const u16* __restrict__ Qb, const u16* __restrict__ Vt,
    float* __restrict__ out) {
  __shared__ __align__(16) u16 plds[2][16 * 40];  // per-wave P tile [16q][32k]
  __shared__ __align__(16) float mrg[64][18];     // wave1: acc16 + m + l
  int lane = threadIdx.x & 63;
  int wv = threadIdx.x >> 6;
  int l15 = lane & 15, g = lane >> 4;
  int b = blockIdx.y;
  int qt = 127 - (int)blockIdx.x;         // heavy q-tiles first
  int qbase = qt * 16;                    // within batch (16 rows per block)

  const u16* Qp = Qb + ((size_t)b * LSEQ + qbase) * HEADD;
  const u16* Kp = Kb + (size_t)b * LSEQ * HEADD;
  const u16* Vp = Vt + (size_t)b * HEADD * LSEQ;

  bf16x8 qf[2];
#pragma unroll
  for (int ds = 0; ds < 2; ++ds)
    qf[ds] = *(const bf16x8*)(Qp + (size_t)l15 * HEADD + 32 * ds + 8 * g);

  f32x4 acc[4] = {};        // [c]: reg r -> q-row qbase+4g+r, col d=16c+l15
  float m = -1e30f, lsum = 0.f;
  int q_abs = qbase + l15;
  int ntiles = (qbase + 47) >> 5;

  for (int t = wv; t < ntiles; t += 2) {
    int kbase = t * 32;
    f32x4 sacc[2] = {};     // [f]: key = kbase+16f+4g+r, q = qbase+l15
#pragma unroll
    for (int f = 0; f < 2; ++f)
#pragma unroll
      for (int ds = 0; ds < 2; ++ds) {
        bf16x8 kf = *(const bf16x8*)(Kp + (size_t)(kbase + 16 * f + l15) * HEADD + 32 * ds + 8 * g);
        sacc[f] = __builtin_amdgcn_mfma_f32_16x16x32_bf16(kf, qf[ds], sacc[f], 0, 0, 0);
      }

    // causal mask + row-max (row == this lane's q)
    float sv[2][4];
    float tmax = -1e30f;
#pragma unroll
    for (int f = 0; f < 2; ++f)
#pragma unroll
      for (int r = 0; r < 4; ++r) {
        int key = kbase + 16 * f + 4 * g + r;
        float s = (key <= q_abs) ? sacc[f][r] : -1e30f;
        sv[f][r] = s;
        tmax = fmaxf(tmax, s);
      }
    tmax = fmaxf(tmax, __shfl_xor(tmax, 16));
    tmax = fmaxf(tmax, __shfl_xor(tmax, 32));
    float mnew = fmaxf(m, tmax);
    float al = __expf(m - mnew);
    float pv[2][4];
    float rs = 0.f;
#pragma unroll
    for (int f = 0; f < 2; ++f)
#pragma unroll
      for (int r = 0; r < 4; ++r) {
        pv[f][r] = __expf(sv[f][r] - mnew);
        rs += pv[f][r];
      }
    rs += __shfl_xor(rs, 16);
    rs += __shfl_xor(rs, 32);
    lsum = lsum * al + rs;
    m = mnew;

    // rescale O accumulator: row 4g+r's factor lives at lane (4g+r)
    float alr[4];
#pragma unroll
    for (int r = 0; r < 4; ++r) alr[r] = __shfl(al, 4 * g + r);
#pragma unroll
    for (int c = 0; c < 4; ++c)
#pragma unroll
      for (int r = 0; r < 4; ++r) acc[c][r] *= alr[r];

    // P -> LDS in PV A-frag layout: P[q=l15][key 16f+4g + r]
#pragma unroll
    for (int f = 0; f < 2; ++f) {
      ushort4 pk;
      pk.x = cvt(pv[f][0]); pk.y = cvt(pv[f][1]);
      pk.z = cvt(pv[f][2]); pk.w = cvt(pv[f][3]);
      *(ushort4*)&plds[wv][l15 * 40 + 16 * f + 4 * g] = pk;
    }
    bf16x8 ap = *(const bf16x8*)&plds[wv][l15 * 40 + 8 * g];

    // PV: B-frag = V[kbase+8g+j][16c+l15] = Vt[16c+l15][kbase+8g+j]
#pragma unroll
    for (int c = 0; c < 4; ++c) {
      bf16x8 vf = *(const bf16x8*)(Vp + (size_t)(16 * c + l15) * LSEQ + kbase + 8 * g);
      acc[c] = __builtin_amdgcn_mfma_f32_16x16x32_bf16(ap, vf, acc[c], 0, 0, 0);
    }
  }

  // ---- split-K merge: wave1 publishes, wave0 combines + stores ----
  if (wv == 1) {
#pragma unroll
    for (int c = 0; c < 4; ++c)
#pragma unroll
      for (int r = 0; r < 4; ++r) mrg[lane][c * 4 + r] = acc[c][r];
    mrg[lane][16] = m;
    mrg[lane][17] = lsum;
  }
  __syncthreads();
  if (wv == 0) {
    float m1 = mrg[lane][16], l1 = mrg[lane][17];
    float mT = fmaxf(m, m1);
    float e0 = __expf(m - mT), e1 = __expf(m1 - mT);  // empty wave1: e1 = 0
    float lT = lsum * e0 + l1 * e1;
    float e0r[4], e1r[4], li[4];
#pragma unroll
    for (int r = 0; r < 4; ++r) {
      e0r[r] = __shfl(e0, 4 * g + r);
      e1r[r] = __shfl(e1, 4 * g + r);
      li[r] = 1.0f / __shfl(lT, 4 * g + r);
    }
#pragma unroll
    for (int c = 0; c < 4; ++c)
#pragma unroll
      for (int r = 0; r < 4; ++r) {
        float v = acc[c][r] * e0r[r] + mrg[lane][c * 4 + r] * e1r[r];
        out[((size_t)b * LSEQ + qbase + 4 * g + r) * HEADD + 16 * c + l15] = v * li[r];
      }
  }
}

// ---------------------------------------------------------------------------
extern "C" void kernel_launch(void* const* d_in, const int* in_sizes, int n_in,
                              void* d_out, int out_size, void* d_ws, size_t ws_size,
                              hipStream_t stream) {
  const float* idx_k = (const float*)d_in[0];
  const float* idx_q = (const float*)d_in[1];
  const float* idx_v = (const float*)d_in[2];
  // d_in[3] = msk : causal mask is applied analytically, never read
  const float* Wk = (const float*)d_in[4];
  const float* Wq = (const float*)d_in[5];
  const float* Wv = (const float*)d_in[6];
  float* out = (float*)d_out;

  char* ws = (char*)d_ws;
  const size_t WT_BYTES = (size_t)3 * 4 * 32 * 512 * 2;          // 384 KB packed W
  const size_t MAT_BYTES = (size_t)NBATCH * LSEQ * HEADD * 2;    // 2 MB each
  u16* wp = (u16*)ws;
  u16* Kb = (u16*)(ws + WT_BYTES);
  u16* Qb = (u16*)(ws + WT_BYTES + MAT_BYTES);
  u16* Vt = (u16*)(ws + WT_BYTES + 2 * MAT_BYTES);

  hipLaunchKernelGGL(wt_kernel, dim3(768), dim3(256), 0, stream, Wk, Wq, Wv, wp);
  hipLaunchKernelGGL(proj_kernel, dim3(256, 3), dim3(256), 0, stream,
                     idx_k, idx_q, idx_v, wp, Kb, Qb, Vt);
  hipLaunchKernelGGL(attn_kernel, dim3(128, NBATCH), dim3(128), 0, stream, Kb, Qb, Vt, out);
}

// Round 11
// 82.047 us; speedup vs baseline: 2.0395x; 1.2547x over previous
//
#include <hip/hip_runtime.h>

typedef __bf16 bf16x8 __attribute__((ext_vector_type(8)));
typedef float f32x4 __attribute__((ext_vector_type(4)));
typedef unsigned short u16;

#define LSEQ 2048
#define DMODEL 1024
#define HEADD 64
#define NBATCH 8

__device__ __forceinline__ u16 cvt(float f) {
  __bf16 h = (__bf16)f;               // native v_cvt (RNE)
  return __builtin_bit_cast(u16, h);
}

// Raw workgroup barrier draining ONLY LDS counters: in-flight global loads
// (the 2-deep A prefetch) survive the barrier.
#define BARRIER_LGKM() do {                                   \
    asm volatile("s_waitcnt lgkmcnt(0)" ::: "memory");        \
    __builtin_amdgcn_sched_barrier(0);                        \
    __builtin_amdgcn_s_barrier();                             \
    __builtin_amdgcn_sched_barrier(0);                        \
  } while (0)

// ---------------------------------------------------------------------------
// Kernel 0: pack W [1024][64] fp32 into MFMA B-FRAGMENT order (bf16):
//   wp[((p*4 + c)*32 + ks)*512 + lane*8 + j] = W_p[k = ks*32 + 8*(lane>>4) + j]
//                                                  [col = 16*c + (lane&15)]
// ---------------------------------------------------------------------------
__global__ __launch_bounds__(256) void wt_kernel(
    const float* __restrict__ Wk, const float* __restrict__ Wq,
    const float* __restrict__ Wv, u16* __restrict__ wp) {
  int idx = blockIdx.x * 256 + threadIdx.x;   // 0 .. 3*4*32*512-1 (196608)
  int j = idx & 7;
  int lane = (idx >> 3) & 63;
  int ks = (idx >> 9) & 31;
  int c = (idx >> 14) & 3;
  int p = idx >> 16;
  const float* W = (p == 0) ? Wk : ((p == 1) ? Wq : Wv);
  int k = ks * 32 + 8 * (lane >> 4) + j;
  int col = 16 * c + (lane & 15);
  wp[idx] = cvt(W[(size_t)k * HEADD + col]);
}

// ---------------------------------------------------------------------------
// Kernel 1: projections. 32-row / 2-wave blocks for occupancy+decorrelation:
// grid 512x3 = 1536 blocks -> 6 blocks/CU, 12 waves/CU (was 2.7 blocks, 27%).
// Same validated skeleton as R10: 2-deep A prefetch (stgA/stgB), W-frags
// loaded first each chunk (vmcnt FIFO), lgkm-only barriers so A loads stay
// in flight across chunk boundaries. LDS: [32][128] bf16 dbuf, XOR-swizzled.
// p==0 -> K bf16 ; p==1 -> Q*0.125 ; p==2 -> V^T [b][64][2048]
// ---------------------------------------------------------------------------
__global__ __launch_bounds__(128) void proj_kernel(
    const float* __restrict__ ik, const float* __restrict__ iq, const float* __restrict__ iv,
    const u16* __restrict__ wp, u16* __restrict__ Kb, u16* __restrict__ Qb,
    u16* __restrict__ Vt) {
  __shared__ __align__(16) u16 Asw[2][32 * 128];  // 2 x 8 KB swizzled bf16
  int p = blockIdx.y;
  const float* A = (p == 0) ? ik : ((p == 1) ? iq : iv);
  const u16* Wp = wp + (size_t)p * 4 * 32 * 512;   // [c][ks_glob][512]
  int t = threadIdx.x;                // 0..127
  int lane = t & 63;
  int wv = t >> 6;
  int l15 = lane & 15, g = lane >> 4;
  int rowbase = blockIdx.x * 32;
  const float* srcbase = A + (size_t)rowbase * DMODEL;

  // A staging map: piece i (0..7): row = i*4 + (t>>5), float-col = (t&31)*4
  int srow0 = t >> 5;                 // 0..3
  int scol = (t & 31) * 4;

  float4 stgA[8], stgB[8];
  bf16x8 wfr[4][4];

  auto issue = [&](float4 (&stg)[8], int kc) {
#pragma unroll
    for (int i = 0; i < 8; ++i)
      stg[i] = *(const float4*)(srcbase + (size_t)(i * 4 + srow0) * DMODEL + kc + scol);
  };
  auto commit = [&](const float4 (&stg)[8], u16* basep) {
    char* base = (char*)basep;
#pragma unroll
    for (int i = 0; i < 8; ++i) {
      int row = i * 4 + srow0;
      ushort4 pk;
      pk.x = cvt(stg[i].x); pk.y = cvt(stg[i].y);
      pk.z = cvt(stg[i].z); pk.w = cvt(stg[i].w);
      int byte = row * 256 + ((scol * 2) ^ ((row & 7) << 4));
      *(ushort4*)(base + byte) = pk;
    }
  };
  auto wload = [&](int c8) {
#pragma unroll
    for (int ks = 0; ks < 4; ++ks)
#pragma unroll
      for (int c = 0; c < 4; ++c)
        wfr[ks][c] = *(const bf16x8*)(Wp + ((size_t)c * 32 + c8 * 4 + ks) * 512 + lane * 8);
  };

  f32x4 acc[4] = {};  // [c]: row = rowbase+16wv+4g+r, col = 16c+l15
  int abase = (16 * wv + l15) * 256;
  int aswz = (l15 & 7) << 4;

  auto computeC = [&](const char* lbase) {
#pragma unroll
    for (int ks = 0; ks < 4; ++ks) {
      bf16x8 af = *(const bf16x8*)(lbase + abase + ((ks * 64 + 16 * g) ^ aswz));
#pragma unroll
      for (int c = 0; c < 4; ++c)
        acc[c] = __builtin_amdgcn_mfma_f32_16x16x32_bf16(af, wfr[ks][c], acc[c], 0, 0, 0);
    }
  };

  // prologue: stgA=kc0, stgB=kc1; commit kc0; barrier
  issue(stgA, 0);
  issue(stgB, 128);
  commit(stgA, &Asw[0][0]);
  BARRIER_LGKM();

#pragma unroll 1
  for (int cc = 0; cc < 8; cc += 2) {
    // ---- even chunk c8 = cc : compute buf0 ----
    wload(cc);                                   // oldest in vmcnt queue
    __builtin_amdgcn_sched_barrier(0);
    if (cc < 6) issue(stgA, (cc + 2) * 128);     // youngest: in flight 2 phases
    __builtin_amdgcn_sched_barrier(0);
    computeC((const char*)&Asw[0][0]);
    commit(stgB, &Asw[1][0]);                    // kc = cc+1 (landed long ago)
    BARRIER_LGKM();
    // ---- odd chunk c8 = cc+1 : compute buf1 ----
    wload(cc + 1);
    __builtin_amdgcn_sched_barrier(0);
    if (cc < 5) issue(stgB, (cc + 3) * 128);
    __builtin_amdgcn_sched_barrier(0);
    computeC((const char*)&Asw[1][0]);
    if (cc < 6) commit(stgA, &Asw[0][0]);        // kc = cc+2
    BARRIER_LGKM();
  }

  int rb2 = rowbase + 16 * wv;
  if (p == 2) {
    // store V transposed: Vt[b][d][tok], pack 4 consecutive tokens -> 8B store
    int row0 = rb2 + 4 * g;
    int b = row0 >> 11, tok = row0 & 2047;
#pragma unroll
    for (int c = 0; c < 4; ++c) {
      int d = 16 * c + l15;
      ushort4 pk;
      pk.x = cvt(acc[c][0]); pk.y = cvt(acc[c][1]);
      pk.z = cvt(acc[c][2]); pk.w = cvt(acc[c][3]);
      *(ushort4*)(Vt + ((size_t)b * HEADD + d) * LSEQ + tok) = pk;
    }
  } else {
    u16* dst = (p == 0) ? Kb : Qb;
    float s = (p == 1) ? 0.125f : 1.0f;  // fold softmax scale into Q (exact pow2)
#pragma unroll
    for (int c = 0; c < 4; ++c)
#pragma unroll
      for (int r = 0; r < 4; ++r)
        dst[(size_t)(rb2 + 4 * g + r) * HEADD + 16 * c + l15] = cvt(acc[c][r] * s);
  }
}

// ---------------------------------------------------------------------------
// Kernel 2: causal flash attention, split-K + XCD-AWARE SWIZZLE.
// 1D grid of 1024 blocks; b = id & 7 so all blocks of batch b land on XCD b
// (round-robin id%8) -> each XCD's L2 holds exactly one batch's K/Q/V
// (~1.3MB < 4MB) and K/V loads become L2 hits instead of L3-thrash.
// Block = 2 waves sharing one 16-row q-tile; wave w handles tiles t%2==w;
// merge (m,l,acc) via LDS. Swapped QK^T; V^T contiguous B-frags.
// ---------------------------------------------------------------------------
__global__ __launch_bounds__(128) void attn_kernel(
    const u16* __restrict__ Kb, const u16* __restrict__ Qb, const u16* __restrict__ Vt,
    float* __restrict__ out) {
  __shared__ __align__(16) u16 plds[2][16 * 40];  // per-wave P tile [16q][32k]
  __shared__ __align__(16) float mrg[64][18];     // wave1: acc16 + m + l
  int lane = threadIdx.x & 63;
  int wv = threadIdx.x >> 6;
  int l15 = lane & 15, g = lane >> 4;
  int id = blockIdx.x;                    // 0..1023
  int b = id & 7;                         // XCD-aligned batch
  int qt = 127 - (id >> 3);               // heavy q-tiles first
  int qbase = qt * 16;                    // within batch (16 rows per block)

  const u16* Qp = Qb + ((size_t)b * LSEQ + qbase) * HEADD;
  const u16* Kp = Kb + (size_t)b * LSEQ * HEADD;
  const u16* Vp = Vt + (size_t)b * HEADD * LSEQ;

  bf16x8 qf[2];
#pragma unroll
  for (int ds = 0; ds < 2; ++ds)
    qf[ds] = *(const bf16x8*)(Qp + (size_t)l15 * HEADD + 32 * ds + 8 * g);

  f32x4 acc[4] = {};        // [c]: reg r -> q-row qbase+4g+r, col d=16c+l15
  float m = -1e30f, lsum = 0.f;
  int q_abs = qbase + l15;
  int ntiles = (qbase + 47) >> 5;

  for (int t = wv; t < ntiles; t += 2) {
    int kbase = t * 32;
    f32x4 sacc[2] = {};     // [f]: key = kbase+16f+4g+r, q = qbase+l15
#pragma unroll
    for (int f = 0; f < 2; ++f)
#pragma unroll
      for (int ds = 0; ds < 2; ++ds) {
        bf16x8 kf = *(const bf16x8*)(Kp + (size_t)(kbase + 16 * f + l15) * HEADD + 32 * ds + 8 * g);
        sacc[f] = __builtin_amdgcn_mfma_f32_16x16x32_bf16(kf, qf[ds], sacc[f], 0, 0, 0);
      }

    // causal mask + row-max (row == this lane's q)
    float sv[2][4];
    float tmax = -1e30f;
#pragma unroll
    for (int f = 0; f < 2; ++f)
#pragma unroll
      for (int r = 0; r < 4; ++r) {
        int key = kbase + 16 * f + 4 * g + r;
        float s = (key <= q_abs) ? sacc[f][r] : -1e30f;
        sv[f][r] = s;
        tmax = fmaxf(tmax, s);
      }
    tmax = fmaxf(tmax, __shfl_xor(tmax, 16));
    tmax = fmaxf(tmax, __shfl_xor(tmax, 32));
    float mnew = fmaxf(m, tmax);
    float al = __expf(m - mnew);
    float pv[2][4];
    float rs = 0.f;
#pragma unroll
    for (int f = 0; f < 2; ++f)
#pragma unroll
      for (int r = 0; r < 4; ++r) {
        pv[f][r] = __expf(sv[f][r] - mnew);
        rs += pv[f][r];
      }
    rs += __shfl_xor(rs, 16);
    rs += __shfl_xor(rs, 32);
    lsum = lsum * al + rs;
    m = mnew;

    // rescale O accumulator: row 4g+r's factor lives at lane (4g+r)
    float alr[4];
#pragma unroll
    for (int r = 0; r < 4; ++r) alr[r] = __shfl(al, 4 * g + r);
#pragma unroll
    for (int c = 0; c < 4; ++c)
#pragma unroll
      for (int r = 0; r < 4; ++r) acc[c][r] *= alr[r];

    // P -> LDS in PV A-frag layout: P[q=l15][key 16f+4g + r]
#pragma unroll
    for (int f = 0; f < 2; ++f) {
      ushort4 pk;
      pk.x = cvt(pv[f][0]); pk.y = cvt(pv[f][1]);
      pk.z = cvt(pv[f][2]); pk.w = cvt(pv[f][3]);
      *(ushort4*)&plds[wv][l15 * 40 + 16 * f + 4 * g] = pk;
    }
    bf16x8 ap = *(const bf16x8*)&plds[wv][l15 * 40 + 8 * g];

    // PV: B-frag = V[kbase+8g+j][16c+l15] = Vt[16c+l15][kbase+8g+j]
#pragma unroll
    for (int c = 0; c < 4; ++c) {
      bf16x8 vf = *(const bf16x8*)(Vp + (size_t)(16 * c + l15) * LSEQ + kbase + 8 * g);
      acc[c] = __builtin_amdgcn_mfma_f32_16x16x32_bf16(ap, vf, acc[c], 0, 0, 0);
    }
  }

  // ---- split-K merge: wave1 publishes, wave0 combines + stores ----
  if (wv == 1) {
#pragma unroll
    for (int c = 0; c < 4; ++c)
#pragma unroll
      for (int r = 0; r < 4; ++r) mrg[lane][c * 4 + r] = acc[c][r];
    mrg[lane][16] = m;
    mrg[lane][17] = lsum;
  }
  __syncthreads();
  if (wv == 0) {
    float m1 = mrg[lane][16], l1 = mrg[lane][17];
    float mT = fmaxf(m, m1);
    float e0 = __expf(m - mT), e1 = __expf(m1 - mT);  // empty wave1: e1 = 0
    float lT = lsum * e0 + l1 * e1;
    float e0r[4], e1r[4], li[4];
#pragma unroll
    for (int r = 0; r < 4; ++r) {
      e0r[r] = __shfl(e0, 4 * g + r);
      e1r[r] = __shfl(e1, 4 * g + r);
      li[r] = 1.0f / __shfl(lT, 4 * g + r);
    }
#pragma unroll
    for (int c = 0; c < 4; ++c)
#pragma unroll
      for (int r = 0; r < 4; ++r) {
        float v = acc[c][r] * e0r[r] + mrg[lane][c * 4 + r] * e1r[r];
        out[((size_t)b * LSEQ + qbase + 4 * g + r) * HEADD + 16 * c + l15] = v * li[r];
      }
  }
}

// ---------------------------------------------------------------------------
extern "C" void kernel_launch(void* const* d_in, const int* in_sizes, int n_in,
                              void* d_out, int out_size, void* d_ws, size_t ws_size,
                              hipStream_t stream) {
  const float* idx_k = (const float*)d_in[0];
  const float* idx_q = (const float*)d_in[1];
  const float* idx_v = (const float*)d_in[2];
  // d_in[3] = msk : causal mask is applied analytically, never read
  const float* Wk = (const float*)d_in[4];
  const float* Wq = (const float*)d_in[5];
  const float* Wv = (const float*)d_in[6];
  float* out = (float*)d_out;

  char* ws = (char*)d_ws;
  const size_t WT_BYTES = (size_t)3 * 4 * 32 * 512 * 2;          // 384 KB packed W
  const size_t MAT_BYTES = (size_t)NBATCH * LSEQ * HEADD * 2;    // 2 MB each
  u16* wp = (u16*)ws;
  u16* Kb = (u16*)(ws + WT_BYTES);
  u16* Qb = (u16*)(ws + WT_BYTES + MAT_BYTES);
  u16* Vt = (u16*)(ws + WT_BYTES + 2 * MAT_BYTES);

  hipLaunchKernelGGL(wt_kernel, dim3(768), dim3(256), 0, stream, Wk, Wq, Wv, wp);
  hipLaunchKernelGGL(proj_kernel, dim3(512, 3), dim3(128), 0, stream,
                     idx_k, idx_q, idx_v, wp, Kb, Qb, Vt);
  hipLaunchKernelGGL(attn_kernel, dim3(1024), dim3(128), 0, stream, Kb, Qb, Vt, out);
}